// Round 11
// baseline (98.640 us; speedup 1.0000x reference)
//
#include <hip/hip_runtime.h>
#include <hip/hip_bf16.h>

typedef __attribute__((ext_vector_type(8))) short short8;
typedef __attribute__((ext_vector_type(4))) float f32x4;

#define ALPHA 0.2f
#define NEG_INF -9e15f
#define OUT 62                // output rows per tile (64 staged incl. halo)
#define NTILES 1058           // ceil(65536/62)
#define NB 4
#define NN 65536

__device__ __forceinline__ short fb(float x) {
    __hip_bfloat16 b = __float2bfloat16(x);
    return __builtin_bit_cast(short, b);
}
__device__ __forceinline__ float bf2f(unsigned short x) {
    union { unsigned int u; float f; } v; v.u = ((unsigned int)x) << 16;
    return v.f;
}

// prep: W -> bf16 B-fragment table (frag fi = kk*8+q, q = 16-col block) at
// shorts[0..16383]; [Wa1|Wa2|0..] column-fragment table at shorts[16384..].
__global__ __launch_bounds__(256) void prep_w(const float* __restrict__ W,
                                              const float* __restrict__ a,
                                              unsigned short* __restrict__ ws) {
    const int t = threadIdx.x;
    if (blockIdx.x < 8) {
        int qg = blockIdx.x * 256 + t;       // 0..2047
        int lane = qg & 63, fi = qg >> 6;
        int q = fi & 7, kk = fi >> 3;
        int n = q * 16 + (lane & 15);
        int k0 = kk * 32 + ((lane >> 4) & 3) * 8;
        short8 o;
        #pragma unroll
        for (int j = 0; j < 8; ++j) o[j] = fb(W[(k0 + j) * 128 + n]);
        *(short8*)(ws + (size_t)qg * 8) = o;
    } else {
        __shared__ float wa[2][128];
        {
            int k = t >> 1, sel = t & 1;
            const f32x4* wr4 = (const f32x4*)(W + k * 128);
            const f32x4* av4 = (const f32x4*)(a + sel * 128);
            float s = 0.f;
            #pragma unroll
            for (int c4 = 0; c4 < 32; ++c4) {
                f32x4 wv = wr4[c4], av = av4[c4];
                s += wv[0]*av[0] + wv[1]*av[1] + wv[2]*av[2] + wv[3]*av[3];
            }
            wa[sel][k] = s;
        }
        __syncthreads();
        {
            int lane = t & 63, kk = t >> 6;
            int l15 = lane & 15, lg = (lane >> 4) & 3;
            int k0 = kk * 32 + lg * 8;
            short8 o;
            #pragma unroll
            for (int j = 0; j < 8; ++j) o[j] = fb((l15 < 2) ? wa[l15][k0 + j] : 0.f);
            *(short8*)(ws + 16384 + (size_t)t * 8) = o;
        }
    }
}

// Stage-free kernel: A-fragments load directly global->reg (coalesced: 16
// rows x 128B contiguous per wave instruction), GEMM, bf16 Wh spill to LDS,
// ONE barrier, combine+store. LDS ~17.5KB; occupancy VGPR-bound only.
__global__ __launch_bounds__(256, 2)
void gat_fused(const float* __restrict__ h, const int* __restrict__ opm,
               const unsigned short* __restrict__ ws, float* __restrict__ out) {
    __shared__ __align__(16) char Bw[16384];     // Wh bf16, swizzled
    __shared__ float wh1s[64];
    __shared__ float wh2s[72];                   // row r at 4+r
    __shared__ int maskL[186];

    const int t = threadIdx.x;
    const int lane = t & 63;
    const int w = t >> 6;
    const int l15 = lane & 15;
    const int lg = (lane >> 4) & 3;
    const int C = w << 5;              // col base: 0/32/64/96

    const int blk = blockIdx.x;
    const int b = blk / NTILES;
    const int tile = blk - b * NTILES;
    const int row_start = tile * OUT;
    const int base = row_start - 1;
    const int out_rows = min(OUT, NN - row_start);
    float* outB = out + (size_t)b * NN * 128;

    // ---- masks to registers (issued early, written to LDS pre-barrier) ----
    int mreg = 0;
    if (t < 186) {
        int idx = row_start * 3 + t;
        if (idx > NN * 3 - 1) idx = NN * 3 - 1;
        mreg = opm[(size_t)b * (NN * 3) + idx];
    }

    // ---- B fragments (L2/L3-hot table) ----
    const short8* wsv  = (const short8*)ws;
    const short8* wsv2 = (const short8*)(ws + 16384);
    short8 bfr[4][2], bfr2[4];
    #pragma unroll
    for (int kk = 0; kk < 4; ++kk) {
        #pragma unroll
        for (int ni = 0; ni < 2; ++ni)
            bfr[kk][ni] = wsv[(size_t)(((kk << 3) + (w << 1) + ni) * 64 + lane)];
        bfr2[kk] = wsv2[(size_t)((kk << 6) + lane)];
    }

    // ---- per-lane row pointers for direct A-fragment loads ----
    const char* hB = (const char*)(h + (size_t)b * NN * 128);
    const char* rp[4];
    #pragma unroll
    for (int mi = 0; mi < 4; ++mi) {
        int m = (mi << 4) + l15;
        int g = base + m;
        if (g < 0) g += NN; else if (g >= NN) g -= NN;
        rp[mi] = hB + (size_t)g * 512 + (lg << 5);
    }

    // ---- GEMM: Wh[64][128], A from global, B from registers ----
    f32x4 acc[4][2];
    f32x4 acc2[4];
    #pragma unroll
    for (int mi = 0; mi < 4; ++mi) {
        acc2[mi] = (f32x4){0.f, 0.f, 0.f, 0.f};
        #pragma unroll
        for (int ni = 0; ni < 2; ++ni)
            acc[mi][ni] = (f32x4){0.f, 0.f, 0.f, 0.f};
    }
    #pragma unroll
    for (int kk = 0; kk < 4; ++kk) {
        short8 af[4];
        #pragma unroll
        for (int mi = 0; mi < 4; ++mi) {
            f32x4 lo = *(const f32x4*)(rp[mi] + (kk << 7));
            f32x4 hi = *(const f32x4*)(rp[mi] + (kk << 7) + 16);
            short8 v;
            v[0] = fb(lo[0]); v[1] = fb(lo[1]); v[2] = fb(lo[2]); v[3] = fb(lo[3]);
            v[4] = fb(hi[0]); v[5] = fb(hi[1]); v[6] = fb(hi[2]); v[7] = fb(hi[3]);
            af[mi] = v;
        }
        #pragma unroll
        for (int mi = 0; mi < 4; ++mi) {
            #pragma unroll
            for (int ni = 0; ni < 2; ++ni)
                acc[mi][ni] = __builtin_amdgcn_mfma_f32_16x16x32_bf16(
                    af[mi], bfr[kk][ni], acc[mi][ni], 0, 0, 0);
            if (w == 0)
                acc2[mi] = __builtin_amdgcn_mfma_f32_16x16x32_bf16(
                    af[mi], bfr2[kk], acc2[mi], 0, 0, 0);
        }
    }

    // ---- pre-barrier LDS writes: masks, Wh spill (bf16 swizzled), wh1/wh2 ----
    if (t < 186) maskL[t] = mreg;
    #pragma unroll
    for (int mi = 0; mi < 4; ++mi)
        #pragma unroll
        for (int ni = 0; ni < 2; ++ni) {
            int col = C + (ni << 4) + l15;
            #pragma unroll
            for (int j = 0; j < 4; ++j) {
                int row = (mi << 4) + (lg << 2) + j;
                *(unsigned short*)(Bw + row * 256 + ((col << 1) ^ ((row & 7) << 4))) =
                    (unsigned short)fb(acc[mi][ni][j]);
            }
        }
    if (w == 0 && l15 < 2) {
        float* dst = (l15 == 0) ? wh1s : (wh2s + 4);
        #pragma unroll
        for (int mi = 0; mi < 4; ++mi)
            #pragma unroll
            for (int j = 0; j < 4; ++j)
                dst[(mi << 4) + (lg << 2) + j] = acc2[mi][j];
    }
    __syncthreads();   // the only barrier

    // ---- combine: inline softmax + coalesced f32x4 stores ----
    #pragma unroll
    for (int it = 0; it < 8; ++it) {
        int r = 1 + (t >> 5) + (it << 3);
        if (r > out_rows) continue;
        int g = base + r;
        int mk0 = maskL[(r - 1) * 3];
        int mk1 = maskL[(r - 1) * 3 + 1];
        int mk2 = maskL[(r - 1) * 3 + 2];
        float w1 = wh1s[r];
        float e0 = w1 + wh2s[3 + r];
        float e1 = w1 + wh2s[4 + r];
        float e2 = w1 + wh2s[5 + r];
        e0 = e0 > 0.f ? e0 : ALPHA * e0;
        e1 = e1 > 0.f ? e1 : ALPHA * e1;
        e2 = e2 > 0.f ? e2 : ALPHA * e2;
        if (mk0 > 0) e0 = NEG_INF;
        if (mk1 > 0) e1 = NEG_INF;
        if (mk2 > 0) e2 = NEG_INF;
        float m = fmaxf(e0, fmaxf(e1, e2));
        float x0 = __expf(e0 - m), x1 = __expf(e1 - m), x2 = __expf(e2 - m);
        float inv = 1.f / (x0 + x1 + x2);
        float a0 = x0 * inv, a1 = x1 * inv, a2 = x2 * inv;
        int cb = (t & 31) << 3;
        ushort4 wm = *(const ushort4*)(Bw + (r - 1) * 256 + (cb ^ (((r - 1) & 7) << 4)));
        ushort4 w0 = *(const ushort4*)(Bw + r * 256 + (cb ^ ((r & 7) << 4)));
        ushort4 wp = *(const ushort4*)(Bw + (r + 1) * 256 + (cb ^ (((r + 1) & 7) << 4)));
        f32x4 res;
        res[0] = a0 * bf2f(wm.x) + a1 * bf2f(w0.x) + a2 * bf2f(wp.x);
        res[1] = a0 * bf2f(wm.y) + a1 * bf2f(w0.y) + a2 * bf2f(wp.y);
        res[2] = a0 * bf2f(wm.z) + a1 * bf2f(w0.z) + a2 * bf2f(wp.z);
        res[3] = a0 * bf2f(wm.w) + a1 * bf2f(w0.w) + a2 * bf2f(wp.w);
        *(f32x4*)(outB + (size_t)g * 128 + ((t & 31) << 2)) = res;
    }
}

extern "C" void kernel_launch(void* const* d_in, const int* in_sizes, int n_in,
                              void* d_out, int out_size, void* d_ws, size_t ws_size,
                              hipStream_t stream) {
    const float* h   = (const float*)d_in[0];
    const int*   opm = (const int*)d_in[1];
    const float* W   = (const float*)d_in[2];
    const float* a   = (const float*)d_in[3];
    float* out = (float*)d_out;
    unsigned short* ws = (unsigned short*)d_ws;
    prep_w<<<9, 256, 0, stream>>>(W, a, ws);
    gat_fused<<<NTILES * NB, 256, 0, stream>>>(h, opm, ws, out);
}

// Round 12
// 70.061 us; speedup vs baseline: 1.4079x; 1.4079x over previous
//
#include <hip/hip_runtime.h>
#include <hip/hip_bf16.h>

typedef __attribute__((ext_vector_type(8))) short short8;
typedef __attribute__((ext_vector_type(4))) float f32x4;

#define ALPHA 0.2f
#define NEG_INF -9e15f
#define QB 14                 // output rows per wave-tile
#define NB 4
#define NN 65536
#define TPB 4682              // ceil(NN/QB)
#define TTOT (TPB * NB)       // 18728 wave-tiles
#define NBLK 512              // persistent blocks (2/CU)
#define WPB 8                 // waves per block (512 threads)
#define NWAVES (NBLK * WPB)   // 4096

__device__ __forceinline__ short fb(float x) {
    __hip_bfloat16 b = __float2bfloat16(x);
    return __builtin_bit_cast(short, b);
}
__device__ __forceinline__ float bf2f(unsigned short x) {
    union { unsigned int u; float f; } v; v.u = ((unsigned int)x) << 16;
    return v.f;
}

// prep: 36 fragment slots, slot s = kk*9 + ni.
//   ni<8 : elem j = W[kk*32 + lg*8 + j][ni*16 + l15]
//   ni=8 : elem j = (l15==0 ? Wa1 : l15==1 ? Wa2 : 0)[kk*32 + lg*8 + j]
// stored at ws + (s*64 + lane)*16 bytes.
__global__ __launch_bounds__(256) void prep_w(const float* __restrict__ W,
                                              const float* __restrict__ a,
                                              unsigned short* __restrict__ ws) {
    const int t = threadIdx.x;
    if (blockIdx.x < 8) {
        int qg = blockIdx.x * 256 + t;       // 0..2047
        int lane = qg & 63, f = qg >> 6;     // f 0..31
        int kk = f >> 3, ni = f & 7;
        int slot = kk * 9 + ni;
        int n = ni * 16 + (lane & 15);
        int k0 = kk * 32 + ((lane >> 4) & 3) * 8;
        short8 o;
        #pragma unroll
        for (int j = 0; j < 8; ++j) o[j] = fb(W[(k0 + j) * 128 + n]);
        *(short8*)(ws + (size_t)(slot * 64 + lane) * 8) = o;
    } else {
        __shared__ float wa[2][128];
        {
            int k = t >> 1, sel = t & 1;
            const f32x4* wr4 = (const f32x4*)(W + k * 128);
            const f32x4* av4 = (const f32x4*)(a + sel * 128);
            float s = 0.f;
            #pragma unroll
            for (int c4 = 0; c4 < 32; ++c4) {
                f32x4 wv = wr4[c4], av = av4[c4];
                s += wv[0]*av[0] + wv[1]*av[1] + wv[2]*av[2] + wv[3]*av[3];
            }
            wa[sel][k] = s;
        }
        __syncthreads();
        {
            int lane = t & 63, kk = t >> 6;
            int l15 = lane & 15, lg = (lane >> 4) & 3;
            int k0 = kk * 32 + lg * 8;
            int slot = kk * 9 + 8;
            short8 o;
            #pragma unroll
            for (int j = 0; j < 8; ++j) o[j] = fb((l15 < 2) ? wa[l15][k0 + j] : 0.f);
            *(short8*)(ws + (size_t)(slot * 64 + lane) * 8) = o;
        }
    }
}

// Wave-autonomous kernel: each wave owns 16-row windows producing 14 out rows.
// ZERO in-loop barriers: B-table in LDS (loaded once), Wh spill + masks go to
// a wave-private LDS strip (in-wave lgkmcnt only, compiler-inserted).
__global__ __launch_bounds__(512)
void gat_fused(const float* __restrict__ h, const int* __restrict__ opm,
               const unsigned short* __restrict__ ws, float* __restrict__ out) {
    __shared__ __align__(16) char Btab[36864];      // 36 frags x 64 lanes x 16B
    __shared__ __align__(16) char strip[WPB][4096]; // Wh bf16 16 rows x 256B
    __shared__ float whs[WPB][32];                  // wh1/wh2: [row*2 + sel]
    __shared__ int   msk[WPB][44];

    const int t = threadIdx.x;
    const int lane = t & 63;
    const int w = t >> 6;
    const int l15 = lane & 15;
    const int lg = (lane >> 4) & 3;

    // ---- load B fragment table (once), the ONLY barrier ----
    #pragma unroll
    for (int i = 0; i < 5; ++i) {
        int idx = t + i * 512;
        if (idx < 2304) ((f32x4*)Btab)[idx] = ((const f32x4*)ws)[idx];
    }
    __syncthreads();
    const short8* Bt = (const short8*)Btab;
    char* st = strip[w];

    for (int wt = blockIdx.x * WPB + w; wt < TTOT; wt += NWAVES) {
        const int b = wt / TPB;
        const int tt = wt - b * TPB;
        const int out0 = tt * QB;
        const int orows = min(QB, NN - out0);
        const int base = out0 - 1;                  // window row 0
        const char* hB = (const char*)(h + (size_t)b * NN * 128);
        float* outB = out + (size_t)b * NN * 128;

        // ---- issue A loads (8 x f32x4, all in flight) ----
        int g = base + l15;
        if (g < 0) g += NN; else if (g >= NN) g -= NN;
        const char* rp = hB + (size_t)g * 512 + (lg << 5);
        f32x4 al[4][2];
        #pragma unroll
        for (int kk = 0; kk < 4; ++kk) {
            al[kk][0] = *(const f32x4*)(rp + (kk << 7));
            al[kk][1] = *(const f32x4*)(rp + (kk << 7) + 16);
        }
        // ---- masks -> wave strip ----
        if (lane < 42) {
            int mi_ = out0 * 3 + lane;
            if (mi_ > NN * 3 - 1) mi_ = NN * 3 - 1;
            msk[w][lane] = opm[(size_t)b * (NN * 3) + mi_];
        }

        // ---- GEMM: 16 rows x 128 cols (+ wh column) ----
        f32x4 acc[8];
        f32x4 acc2 = (f32x4){0.f, 0.f, 0.f, 0.f};
        #pragma unroll
        for (int ni = 0; ni < 8; ++ni) acc[ni] = (f32x4){0.f, 0.f, 0.f, 0.f};
        #pragma unroll
        for (int kk = 0; kk < 4; ++kk) {
            short8 av;
            av[0] = fb(al[kk][0][0]); av[1] = fb(al[kk][0][1]);
            av[2] = fb(al[kk][0][2]); av[3] = fb(al[kk][0][3]);
            av[4] = fb(al[kk][1][0]); av[5] = fb(al[kk][1][1]);
            av[6] = fb(al[kk][1][2]); av[7] = fb(al[kk][1][3]);
            #pragma unroll
            for (int ni = 0; ni < 8; ++ni)
                acc[ni] = __builtin_amdgcn_mfma_f32_16x16x32_bf16(
                    av, Bt[(kk * 9 + ni) * 64 + lane], acc[ni], 0, 0, 0);
            acc2 = __builtin_amdgcn_mfma_f32_16x16x32_bf16(
                av, Bt[(kk * 9 + 8) * 64 + lane], acc2, 0, 0, 0);
        }

        // ---- spill Wh (bf16) into wave strip; swizzle byte ^= (row&4)<<4 ----
        // C/D layout: col = lane&15, row = lg*4 + j  [HW-verified]
        #pragma unroll
        for (int ni = 0; ni < 8; ++ni) {
            int col = (ni << 4) + l15;
            #pragma unroll
            for (int j = 0; j < 4; ++j) {
                int row = (lg << 2) + j;
                *(unsigned short*)(st + row * 256 + ((col << 1) ^ ((row & 4) << 4))) =
                    (unsigned short)fb(acc[ni][j]);
            }
        }
        if (l15 < 2) {
            #pragma unroll
            for (int j = 0; j < 4; ++j)
                whs[w][((lg << 2) + j) * 2 + l15] = acc2[j];
        }

        // ---- combine (wave-local reads; compiler inserts lgkm waits) ----
        #pragma unroll
        for (int it = 0; it < 7; ++it) {
            int rr = (it << 1) + (lane >> 5);       // out row offset 0..13
            if (rr >= orows) continue;
            int r = rr + 1;                          // window row
            int mk0 = msk[w][rr * 3];
            int mk1 = msk[w][rr * 3 + 1];
            int mk2 = msk[w][rr * 3 + 2];
            float w1 = whs[w][r * 2];
            float e0 = w1 + whs[w][(r - 1) * 2 + 1];
            float e1 = w1 + whs[w][r * 2 + 1];
            float e2 = w1 + whs[w][(r + 1) * 2 + 1];
            e0 = e0 > 0.f ? e0 : ALPHA * e0;
            e1 = e1 > 0.f ? e1 : ALPHA * e1;
            e2 = e2 > 0.f ? e2 : ALPHA * e2;
            if (mk0 > 0) e0 = NEG_INF;
            if (mk1 > 0) e1 = NEG_INF;
            if (mk2 > 0) e2 = NEG_INF;
            float m = fmaxf(e0, fmaxf(e1, e2));
            float x0 = __expf(e0 - m), x1 = __expf(e1 - m), x2 = __expf(e2 - m);
            float inv = 1.f / (x0 + x1 + x2);
            float a0 = x0 * inv, a1 = x1 * inv, a2 = x2 * inv;
            int cb = (lane & 31) << 3;
            ushort4 wm = *(const ushort4*)(st + (r - 1) * 256 + (cb ^ (((r - 1) & 4) << 4)));
            ushort4 w0 = *(const ushort4*)(st + r * 256 + (cb ^ ((r & 4) << 4)));
            ushort4 wp = *(const ushort4*)(st + (r + 1) * 256 + (cb ^ (((r + 1) & 4) << 4)));
            f32x4 res;
            res[0] = a0 * bf2f(wm.x) + a1 * bf2f(w0.x) + a2 * bf2f(wp.x);
            res[1] = a0 * bf2f(wm.y) + a1 * bf2f(w0.y) + a2 * bf2f(wp.y);
            res[2] = a0 * bf2f(wm.z) + a1 * bf2f(w0.z) + a2 * bf2f(wp.z);
            res[3] = a0 * bf2f(wm.w) + a1 * bf2f(w0.w) + a2 * bf2f(wp.w);
            *(f32x4*)(outB + (size_t)(out0 + rr) * 128 + ((lane & 31) << 2)) = res;
        }
    }
}

extern "C" void kernel_launch(void* const* d_in, const int* in_sizes, int n_in,
                              void* d_out, int out_size, void* d_ws, size_t ws_size,
                              hipStream_t stream) {
    const float* h   = (const float*)d_in[0];
    const int*   opm = (const int*)d_in[1];
    const float* W   = (const float*)d_in[2];
    const float* a   = (const float*)d_in[3];
    float* out = (float*)d_out;
    unsigned short* ws = (unsigned short*)d_ws;
    prep_w<<<9, 256, 0, stream>>>(W, a, ws);
    gat_fused<<<NBLK, 512, 0, stream>>>(h, opm, ws, out);
}

// Round 13
// 60.854 us; speedup vs baseline: 1.6209x; 1.1513x over previous
//
#include <hip/hip_runtime.h>
#include <hip/hip_bf16.h>

typedef __attribute__((ext_vector_type(8))) short short8;
typedef __attribute__((ext_vector_type(4))) float f32x4;

#define ALPHA 0.2f
#define NEG_INF -9e15f
#define QB 14                 // output rows per wave-tile
#define NB 4
#define NN 65536
#define TPB 4682              // ceil(NN/QB)
#define TTOT (TPB * NB)       // 18728 wave-tiles
#define NBLK 512              // persistent blocks (2/CU)
#define WPB 8                 // waves per block (512 threads)
#define NWAVES (NBLK * WPB)   // 4096

__device__ __forceinline__ short fb(float x) {
    __hip_bfloat16 b = __float2bfloat16(x);
    return __builtin_bit_cast(short, b);
}
__device__ __forceinline__ float bf2f(unsigned short x) {
    union { unsigned int u; float f; } v; v.u = ((unsigned int)x) << 16;
    return v.f;
}

// prep: 36 fragment slots, slot s = kk*9 + ni.
//   ni<8 : elem j = W[kk*32 + lg*8 + j][ni*16 + l15]
//   ni=8 : elem j = (l15==0 ? Wa1 : l15==1 ? Wa2 : 0)[kk*32 + lg*8 + j]
__global__ __launch_bounds__(256) void prep_w(const float* __restrict__ W,
                                              const float* __restrict__ a,
                                              unsigned short* __restrict__ ws) {
    const int t = threadIdx.x;
    if (blockIdx.x < 8) {
        int qg = blockIdx.x * 256 + t;       // 0..2047
        int lane = qg & 63, f = qg >> 6;     // f 0..31
        int kk = f >> 3, ni = f & 7;
        int slot = kk * 9 + ni;
        int n = ni * 16 + (lane & 15);
        int k0 = kk * 32 + ((lane >> 4) & 3) * 8;
        short8 o;
        #pragma unroll
        for (int j = 0; j < 8; ++j) o[j] = fb(W[(k0 + j) * 128 + n]);
        *(short8*)(ws + (size_t)(slot * 64 + lane) * 8) = o;
    } else {
        __shared__ float wa[2][128];
        {
            int k = t >> 1, sel = t & 1;
            const f32x4* wr4 = (const f32x4*)(W + k * 128);
            const f32x4* av4 = (const f32x4*)(a + sel * 128);
            float s = 0.f;
            #pragma unroll
            for (int c4 = 0; c4 < 32; ++c4) {
                f32x4 wv = wr4[c4], av = av4[c4];
                s += wv[0]*av[0] + wv[1]*av[1] + wv[2]*av[2] + wv[3]*av[3];
            }
            wa[sel][k] = s;
        }
        __syncthreads();
        {
            int lane = t & 63, kk = t >> 6;
            int l15 = lane & 15, lg = (lane >> 4) & 3;
            int k0 = kk * 32 + lg * 8;
            int slot = kk * 9 + 8;
            short8 o;
            #pragma unroll
            for (int j = 0; j < 8; ++j) o[j] = fb((l15 < 2) ? wa[l15][k0 + j] : 0.f);
            *(short8*)(ws + (size_t)(slot * 64 + lane) * 8) = o;
        }
    }
}

// Wave-autonomous + in-wave pipelined: loads for tile i+1 are issued right
// after tile i's loaded regs are converted, and fly during GEMM+spill+combine.
// Zero in-loop barriers.
__global__ __launch_bounds__(512)
void gat_fused(const float* __restrict__ h, const int* __restrict__ opm,
               const unsigned short* __restrict__ ws, float* __restrict__ out) {
    __shared__ __align__(16) char Btab[36864];      // 36 frags x 64 lanes x 16B
    __shared__ __align__(16) char strip[WPB][4096]; // Wh bf16 16 rows x 256B
    __shared__ float whs[WPB][32];                  // wh1/wh2: [row*2 + sel]
    __shared__ int   msk[WPB][44];

    const int t = threadIdx.x;
    const int lane = t & 63;
    const int w = t >> 6;
    const int l15 = lane & 15;
    const int lg = (lane >> 4) & 3;

    // ---- load B fragment table (once), the ONLY barrier ----
    #pragma unroll
    for (int i = 0; i < 5; ++i) {
        int idx = t + i * 512;
        if (idx < 2304) ((f32x4*)Btab)[idx] = ((const f32x4*)ws)[idx];
    }
    __syncthreads();
    const short8* Bt = (const short8*)Btab;
    char* st = strip[w];

    // ---- prologue: issue loads for first tile ----
    f32x4 al[4][2];
    int mreg = 0;
    {
        int wt = blockIdx.x * WPB + w;
        if (wt < TTOT) {
            int b = wt / TPB;
            int tt = wt - b * TPB;
            int out0 = tt * QB;
            int g = out0 - 1 + l15;
            if (g < 0) g += NN; else if (g >= NN) g -= NN;
            const char* rp = (const char*)(h + (size_t)b * NN * 128) +
                             (size_t)g * 512 + (lg << 5);
            #pragma unroll
            for (int kk = 0; kk < 4; ++kk) {
                al[kk][0] = *(const f32x4*)(rp + (kk << 7));
                al[kk][1] = *(const f32x4*)(rp + (kk << 7) + 16);
            }
            if (lane < 42) {
                int mi_ = out0 * 3 + lane;
                if (mi_ > NN * 3 - 1) mi_ = NN * 3 - 1;
                mreg = opm[(size_t)b * (NN * 3) + mi_];
            }
        }
    }

    for (int wt = blockIdx.x * WPB + w; wt < TTOT; wt += NWAVES) {
        const int b = wt / TPB;
        const int tt = wt - b * TPB;
        const int out0 = tt * QB;
        const int orows = min(QB, NN - out0);
        float* outB = out + (size_t)b * NN * 128;

        // ---- 1. convert landed loads -> bf16 A-fragments (vmcnt consumer) ----
        short8 av[4];
        #pragma unroll
        for (int kk = 0; kk < 4; ++kk) {
            av[kk][0] = fb(al[kk][0][0]); av[kk][1] = fb(al[kk][0][1]);
            av[kk][2] = fb(al[kk][0][2]); av[kk][3] = fb(al[kk][0][3]);
            av[kk][4] = fb(al[kk][1][0]); av[kk][5] = fb(al[kk][1][1]);
            av[kk][6] = fb(al[kk][1][2]); av[kk][7] = fb(al[kk][1][3]);
        }
        // ---- 2. this tile's masks -> wave strip ----
        if (lane < 42) msk[w][lane] = mreg;

        // ---- 3. issue NEXT tile's loads (fly during GEMM+spill+combine) ----
        const int wt2 = wt + NWAVES;
        if (wt2 < TTOT) {
            int b2 = wt2 / TPB;
            int tt2 = wt2 - b2 * TPB;
            int out02 = tt2 * QB;
            int g2 = out02 - 1 + l15;
            if (g2 < 0) g2 += NN; else if (g2 >= NN) g2 -= NN;
            const char* rp2 = (const char*)(h + (size_t)b2 * NN * 128) +
                              (size_t)g2 * 512 + (lg << 5);
            #pragma unroll
            for (int kk = 0; kk < 4; ++kk) {
                al[kk][0] = *(const f32x4*)(rp2 + (kk << 7));
                al[kk][1] = *(const f32x4*)(rp2 + (kk << 7) + 16);
            }
            if (lane < 42) {
                int mi_ = out02 * 3 + lane;
                if (mi_ > NN * 3 - 1) mi_ = NN * 3 - 1;
                mreg = opm[(size_t)b2 * (NN * 3) + mi_];
            }
        }
        __builtin_amdgcn_sched_barrier(0);   // keep load issue above the GEMM

        // ---- 4. GEMM: 16 rows x 128 cols (+ wh column) ----
        f32x4 acc[8];
        f32x4 acc2 = (f32x4){0.f, 0.f, 0.f, 0.f};
        #pragma unroll
        for (int ni = 0; ni < 8; ++ni) acc[ni] = (f32x4){0.f, 0.f, 0.f, 0.f};
        #pragma unroll
        for (int kk = 0; kk < 4; ++kk) {
            #pragma unroll
            for (int ni = 0; ni < 8; ++ni)
                acc[ni] = __builtin_amdgcn_mfma_f32_16x16x32_bf16(
                    av[kk], Bt[(kk * 9 + ni) * 64 + lane], acc[ni], 0, 0, 0);
            acc2 = __builtin_amdgcn_mfma_f32_16x16x32_bf16(
                av[kk], Bt[(kk * 9 + 8) * 64 + lane], acc2, 0, 0, 0);
        }

        // ---- 5. spill Wh (bf16) into wave strip; byte ^= (row&4)<<4 ----
        #pragma unroll
        for (int ni = 0; ni < 8; ++ni) {
            int col = (ni << 4) + l15;
            #pragma unroll
            for (int j = 0; j < 4; ++j) {
                int row = (lg << 2) + j;
                *(unsigned short*)(st + row * 256 + ((col << 1) ^ ((row & 4) << 4))) =
                    (unsigned short)fb(acc[ni][j]);
            }
        }
        if (l15 < 2) {
            #pragma unroll
            for (int j = 0; j < 4; ++j)
                whs[w][((lg << 2) + j) * 2 + l15] = acc2[j];
        }

        // ---- 6. combine (wave-local; compiler inserts lgkm waits) ----
        #pragma unroll
        for (int it = 0; it < 7; ++it) {
            int rr = (it << 1) + (lane >> 5);       // out row offset 0..13
            if (rr >= orows) continue;
            int r = rr + 1;                          // window row
            int mk0 = msk[w][rr * 3];
            int mk1 = msk[w][rr * 3 + 1];
            int mk2 = msk[w][rr * 3 + 2];
            float w1 = whs[w][r * 2];
            float e0 = w1 + whs[w][(r - 1) * 2 + 1];
            float e1 = w1 + whs[w][r * 2 + 1];
            float e2 = w1 + whs[w][(r + 1) * 2 + 1];
            e0 = e0 > 0.f ? e0 : ALPHA * e0;
            e1 = e1 > 0.f ? e1 : ALPHA * e1;
            e2 = e2 > 0.f ? e2 : ALPHA * e2;
            if (mk0 > 0) e0 = NEG_INF;
            if (mk1 > 0) e1 = NEG_INF;
            if (mk2 > 0) e2 = NEG_INF;
            float m = fmaxf(e0, fmaxf(e1, e2));
            float x0 = __expf(e0 - m), x1 = __expf(e1 - m), x2 = __expf(e2 - m);
            float inv = 1.f / (x0 + x1 + x2);
            float a0 = x0 * inv, a1 = x1 * inv, a2 = x2 * inv;
            int cb = (lane & 31) << 3;
            ushort4 wm = *(const ushort4*)(st + (r - 1) * 256 + (cb ^ (((r - 1) & 4) << 4)));
            ushort4 w0 = *(const ushort4*)(st + r * 256 + (cb ^ ((r & 4) << 4)));
            ushort4 wp = *(const ushort4*)(st + (r + 1) * 256 + (cb ^ (((r + 1) & 4) << 4)));
            f32x4 res;
            res[0] = a0 * bf2f(wm.x) + a1 * bf2f(w0.x) + a2 * bf2f(wp.x);
            res[1] = a0 * bf2f(wm.y) + a1 * bf2f(w0.y) + a2 * bf2f(wp.y);
            res[2] = a0 * bf2f(wm.z) + a1 * bf2f(w0.z) + a2 * bf2f(wp.z);
            res[3] = a0 * bf2f(wm.w) + a1 * bf2f(w0.w) + a2 * bf2f(wp.w);
            *(f32x4*)(outB + (size_t)(out0 + rr) * 128 + ((lane & 31) << 2)) = res;
        }
    }
}

extern "C" void kernel_launch(void* const* d_in, const int* in_sizes, int n_in,
                              void* d_out, int out_size, void* d_ws, size_t ws_size,
                              hipStream_t stream) {
    const float* h   = (const float*)d_in[0];
    const int*   opm = (const int*)d_in[1];
    const float* W   = (const float*)d_in[2];
    const float* a   = (const float*)d_in[3];
    float* out = (float*)d_out;
    unsigned short* ws = (unsigned short*)d_ws;
    prep_w<<<9, 256, 0, stream>>>(W, a, ws);
    gat_fused<<<NBLK, 512, 0, stream>>>(h, opm, ws, out);
}